// Round 7
// baseline (272.846 us; speedup 1.0000x reference)
//
#include <hip/hip_runtime.h>

#define T_SEQ 2048
#define NB    8
#define CDIM  1024
#define HDIM  64
#define PPB   80   // partials per batch: sum_{i<32} ceil((i+1)/8)

typedef __attribute__((ext_vector_type(8))) short short8;
typedef __attribute__((ext_vector_type(4))) short short4v;
typedef __attribute__((ext_vector_type(4))) float float4v;

// f32 -> bf16 bits, round-to-nearest-even
__device__ inline short f2bf(float x) {
    unsigned u = __builtin_bit_cast(unsigned int, x);
    u += 0x7FFFu + ((u >> 16) & 1u);
    return (short)(u >> 16);
}
__device__ inline float bf2f(short v) {
    return __builtin_bit_cast(float, ((unsigned)(unsigned short)v) << 16);
}

// async global->LDS DMA, 16 bytes per lane (global_load_lds_dwordx4)
__device__ inline void dma16(const void* g, void* l) {
    __builtin_amdgcn_global_load_lds(
        (const __attribute__((address_space(1))) unsigned int*)g,
        (__attribute__((address_space(3))) unsigned int*)l, 16, 0, 0);
}

// DPP lane-permute within 16-lane rows (VALU pipe, no LDS)
template<int CTRL> __device__ inline float dppf(float v) {
    return __builtin_bit_cast(float,
        __builtin_amdgcn_update_dpp(0, __builtin_bit_cast(int, v), CTRL, 0xF, 0xF, true));
}
__device__ inline float rowmax16(float v) {
    v = fmaxf(v, dppf<0xB1>(v));  v = fmaxf(v, dppf<0x4E>(v));
    v = fmaxf(v, dppf<0x141>(v)); v = fmaxf(v, dppf<0x140>(v));
    return v;
}
__device__ inline float rowsum16(float v) {
    v += dppf<0xB1>(v);  v += dppf<0x4E>(v);
    v += dppf<0x141>(v); v += dppf<0x140>(v);
    return v;
}

// ---------------------------------------------------------------------------
// Kernel 1: fused prep.
//  (a) blocks (qt16<48, jy==0): Wq|Wk|Wv -> Wbt (192,1024) bf16 transposed.
//  (b) all blocks: build packed pre-masked bf16 bias in per-lane fragment
//      order: biasPk[slot(qt16,j)][lane][nt*4+r], masked entries = -1e38
//      (exp underflows to exact 0 in attn; no compare/select in hot loop).
// grid (128, 8), block 256; wave w handles j = jy*4+w.
// ---------------------------------------------------------------------------
__global__ __launch_bounds__(256) void prep_kernel(
    const float* __restrict__ Wq, const float* __restrict__ Wk,
    const float* __restrict__ Wv, const float* __restrict__ rbias,
    short* __restrict__ Wbt, short* __restrict__ biasPk)
{
    const int qt16 = blockIdx.x;
    const int tid  = threadIdx.x;
    const int wave = tid >> 6, lane = tid & 63;
    const int quad = lane >> 4, l16 = lane & 15;

    if (blockIdx.y == 0 && qt16 < 48) {          // (a) weight convert
        __shared__ float tile[64][65];
        const int w  = qt16 >> 4;
        const int k0 = (qt16 & 15) * 64;
        const float* Ws[3] = {Wq, Wk, Wv};
        const float* W = Ws[w];
        const int n  = tid & 63;
        const int kq = tid >> 6;
#pragma unroll
        for (int i = 0; i < 16; ++i)
            tile[kq + i * 4][n] = W[(size_t)(k0 + kq + i * 4) * HDIM + n];
        __syncthreads();
        const int kk = tid & 63;
#pragma unroll
        for (int i = 0; i < 16; ++i) {
            int nn = kq + i * 4;
            Wbt[((size_t)(w * HDIM + nn)) * CDIM + k0 + kk] = f2bf(tile[kk][nn]);
        }
    }

    const int a  = qt16 >> 2;
    const int jw = (int)blockIdx.y * 4 + wave;
    if (jw <= a) {                                // (b) bias pack
        const short SENT = f2bf(-1e38f);
        short8 lo, hi;
#pragma unroll
        for (int nt = 0; nt < 4; ++nt) {
            const int s = jw * 64 + nt * 16 + l16;
#pragma unroll
            for (int r = 0; r < 4; ++r) {
                const int t = qt16 * 16 + quad * 4 + r;
                float rb = rbias[(size_t)t * T_SEQ + s];
                bool ok = (rb > 0.f) || ((t == 0) && (s == 0));
                short v = ok ? f2bf(rb) : SENT;
                if (nt < 2) lo[nt * 4 + r] = v; else hi[(nt - 2) * 4 + r] = v;
            }
        }
        short* dst = biasPk + ((size_t)((2 * a + (qt16 & 3)) * (a + 1) + jw)) * 1024
                   + lane * 16;
        *(short8*)dst = lo;
        *(short8*)(dst + 8) = hi;
    }
}

// ---------------------------------------------------------------------------
// Kernel 2: projection GEMM (unchanged from R6). grid 512, block 512.
// ---------------------------------------------------------------------------
__global__ __launch_bounds__(512) void proj_kernel(
    const float* __restrict__ x, const short* __restrict__ Wbt,
    short* __restrict__ qb, short* __restrict__ kb, short* __restrict__ vtb)
{
    __shared__ short As[2][32 * 64];
    __shared__ short Bs[2][192 * 64];

    const int tid  = threadIdx.x;
    const int wave = tid >> 6, lane = tid & 63;
    const int quad = lane >> 4, l16 = lane & 15;
    const int mt   = wave >> 2;
    const int cg   = wave & 3;
    const int m0   = blockIdx.x * 32;

    const int arow = tid >> 4;
    const int ac   = tid & 15;
    const int asw  = (((ac >> 1) ^ (arow & 7)) * 8) + (ac & 1) * 4;
    const float* xsrc = x + (size_t)(m0 + arow) * CDIM + ac * 4;

    const int brow = tid >> 3;
    const int bsw  = ((tid & 7) ^ (brow & 7)) * 8;

    float4v acc[3];
#pragma unroll
    for (int i = 0; i < 3; ++i) acc[i] = (float4v){0.f, 0.f, 0.f, 0.f};

    {
        float4 a = *(const float4*)xsrc;
#pragma unroll
        for (int i = 0; i < 3; ++i)
            dma16(Wbt + (size_t)(i * 64 + brow) * CDIM + bsw,
                  &Bs[0][i * 4096 + tid * 8]);
        short4v s; s[0]=f2bf(a.x); s[1]=f2bf(a.y); s[2]=f2bf(a.z); s[3]=f2bf(a.w);
        *(short4v*)&As[0][arow * 64 + asw] = s;
    }

    int p = 0;
    for (int kt = 0; kt < 16; ++kt) {
        __syncthreads();
        const bool more = (kt + 1) < 16;
        float4 a;
        if (more) {
            a = *(const float4*)(xsrc + (kt + 1) * 64);
#pragma unroll
            for (int i = 0; i < 3; ++i)
                dma16(Wbt + (size_t)(i * 64 + brow) * CDIM + (kt + 1) * 64 + bsw,
                      &Bs[p ^ 1][i * 4096 + tid * 8]);
        }
#pragma unroll
        for (int ks = 0; ks < 2; ++ks) {
            const int cs = ((ks * 4 + quad) ^ (l16 & 7)) * 8;
            short8 af = *(const short8*)&As[p][(mt * 16 + l16) * 64 + cs];
#pragma unroll
            for (int i = 0; i < 3; ++i) {
                const int ct = cg * 3 + i;
                short8 bf_ = *(const short8*)&Bs[p][(ct * 16 + l16) * 64 + cs];
                acc[i] = __builtin_amdgcn_mfma_f32_16x16x32_bf16(af, bf_, acc[i], 0, 0, 0);
            }
        }
        if (more) {
            short4v s; s[0]=f2bf(a.x); s[1]=f2bf(a.y); s[2]=f2bf(a.z); s[3]=f2bf(a.w);
            *(short4v*)&As[p ^ 1][arow * 64 + asw] = s;
        }
        p ^= 1;
    }

#pragma unroll
    for (int i = 0; i < 3; ++i) {
        const int ctg = cg * 3 + i;
        const int mat = ctg >> 2;
        const int n   = (ctg & 3) * 16 + l16;
#pragma unroll
        for (int r = 0; r < 4; ++r) {
            const int m = m0 + mt * 16 + quad * 4 + r;
            if (mat == 0)      qb[(size_t)m * HDIM + n] = f2bf(acc[i][r] * 0.03125f);
            else if (mat == 1) kb[(size_t)m * HDIM + n] = f2bf(acc[i][r]);
            else {
                int bb = m >> 11, tt = m & (T_SEQ - 1);
                vtb[((size_t)bb * HDIM + n) * T_SEQ + tt] = f2bf(acc[i][r]);
            }
        }
    }
}

// ---------------------------------------------------------------------------
// Kernel 3: flash attention with fused split-K merge.
// Bias via 2 coalesced dwordx4 loads of packed pre-masked bf16 (L2-resident).
// qt64<=7 (single chunk): write out directly. Else: write partials, last
// finisher (device-scope atomic counter) merges and writes out.
// ---------------------------------------------------------------------------
__global__ __launch_bounds__(256) void attn_kernel(
    const short* __restrict__ qb, const short* __restrict__ kb,
    const short* __restrict__ vtb, const short* __restrict__ biasPk,
    float* __restrict__ Op, float2* __restrict__ mlp,
    int* __restrict__ cnt, float* __restrict__ out)
{
    __shared__ short Ks[2][64 * 64];
    __shared__ short Vs[2][64 * 64];
    __shared__ short Ps[4][16][72];
    __shared__ int lastv;

    const int b   = blockIdx.y;
    const int tid = threadIdx.x;
    const int wave = tid >> 6, lane = tid & 63;
    const int quad = lane >> 4, l16 = lane & 15;
    const int swz  = l16 & 7;
    const int srow = tid >> 3;
    const int gchk = ((tid & 7) ^ (srow & 7)) * 8;

    const int bx = (int)(gridDim.x - 1 - blockIdx.x);   // heavy tasks first
    int qt64 = 0, c = bx, cum = 0;
    while (true) { int ch = (qt64 + 8) >> 3; if (c < ch) break; c -= ch; cum += ch; ++qt64; }
    const int j0 = c * 8;
    const int j1 = (j0 + 8 < qt64 + 1) ? j0 + 8 : qt64 + 1;
    const int qrow0 = qt64 * 64 + wave * 16;
    const size_t boff = (size_t)(2 * qt64 + wave) * (qt64 + 1);

    const short* qptr = qb + (size_t)(b * T_SEQ + qrow0 + l16) * HDIM;
    short8 qf0 = *(const short8*)(qptr + quad * 8);
    short8 qf1 = *(const short8*)(qptr + 32 + quad * 8);

    float4v oacc[4];
#pragma unroll
    for (int i = 0; i < 4; ++i) oacc[i] = (float4v){0.f, 0.f, 0.f, 0.f};
    float m_run[4] = {-1e30f, -1e30f, -1e30f, -1e30f};
    float l_run[4] = {0.f, 0.f, 0.f, 0.f};

    {   // prologue: stage tile j0 into buffer 0
        const int s0 = j0 * 64;
#pragma unroll
        for (int i = 0; i < 2; ++i) {
            dma16(kb + (size_t)(b * T_SEQ + s0 + i * 32 + srow) * HDIM + gchk,
                  &Ks[0][i * 2048 + tid * 8]);
            dma16(vtb + (size_t)(b * HDIM + i * 32 + srow) * T_SEQ + s0 + gchk,
                  &Vs[0][i * 2048 + tid * 8]);
        }
    }

    int p = 0;
    for (int j = j0; j < j1; ++j) {
        __syncthreads();

        // 1. packed bias: 2 coalesced 16B loads (issued before DMAs)
        const short* bp = biasPk + (boff + j) * 1024 + lane * 16;
        short8 bl0 = *(const short8*)bp;
        short8 bl1 = *(const short8*)(bp + 8);

        // 2. prefetch next KV tile
        if (j + 1 < j1) {
            const int sn = (j + 1) * 64;
#pragma unroll
            for (int i = 0; i < 2; ++i) {
                dma16(kb + (size_t)(b * T_SEQ + sn + i * 32 + srow) * HDIM + gchk,
                      &Ks[p ^ 1][i * 2048 + tid * 8]);
                dma16(vtb + (size_t)(b * HDIM + i * 32 + srow) * T_SEQ + sn + gchk,
                      &Vs[p ^ 1][i * 2048 + tid * 8]);
            }
        }

        // 3. S = Q K^T from LDS
        float4v sa[4];
#pragma unroll
        for (int nt = 0; nt < 4; ++nt) {
            const int rbase = (nt * 16 + l16) * 64;
            short8 kf0 = *(const short8*)&Ks[p][rbase + ((quad ^ swz) * 8)];
            short8 kf1 = *(const short8*)&Ks[p][rbase + (((4 + quad) ^ swz) * 8)];
            float4v acc_ = {0.f, 0.f, 0.f, 0.f};
            acc_ = __builtin_amdgcn_mfma_f32_16x16x32_bf16(qf0, kf0, acc_, 0, 0, 0);
            acc_ = __builtin_amdgcn_mfma_f32_16x16x32_bf16(qf1, kf1, acc_, 0, 0, 0);
            sa[nt] = acc_;
        }

        // 4. bias add (pre-masked) + online softmax; masked = -1e38 -> exp = 0
        float pm[4][4];
        float mt[4] = {-1e30f, -1e30f, -1e30f, -1e30f};
#pragma unroll
        for (int nt = 0; nt < 4; ++nt)
#pragma unroll
            for (int r = 0; r < 4; ++r) {
                short rv = (nt < 2) ? bl0[nt * 4 + r] : bl1[(nt - 2) * 4 + r];
                float sv = sa[nt][r] + bf2f(rv);
                pm[nt][r] = sv;
                mt[r] = fmaxf(mt[r], sv);
            }
        float alpha[4];
#pragma unroll
        for (int r = 0; r < 4; ++r) {
            float mn = fmaxf(m_run[r], rowmax16(mt[r]));
            alpha[r] = __expf(m_run[r] - mn);
            m_run[r] = mn;
        }
        float rs[4] = {0.f, 0.f, 0.f, 0.f};
#pragma unroll
        for (int nt = 0; nt < 4; ++nt)
#pragma unroll
            for (int r = 0; r < 4; ++r) {
                float pv = __expf(pm[nt][r] - m_run[r]);
                pm[nt][r] = pv;
                rs[r] += pv;
            }
#pragma unroll
        for (int r = 0; r < 4; ++r) {
            l_run[r] = l_run[r] * alpha[r] + rowsum16(rs[r]);
            oacc[0][r] *= alpha[r]; oacc[1][r] *= alpha[r];
            oacc[2][r] *= alpha[r]; oacc[3][r] *= alpha[r];
        }

        // 5. P (C-layout) -> per-wave LDS -> A-layout; O += P V
#pragma unroll
        for (int nt = 0; nt < 4; ++nt)
#pragma unroll
            for (int r = 0; r < 4; ++r)
                Ps[wave][quad * 4 + r][nt * 16 + l16] = f2bf(pm[nt][r]);

#pragma unroll
        for (int ks = 0; ks < 2; ++ks) {
            short8 pf = *(const short8*)&Ps[wave][l16][ks * 32 + quad * 8];
#pragma unroll
            for (int ht = 0; ht < 4; ++ht) {
                short8 vf = *(const short8*)&Vs[p][(ht * 16 + l16) * 64
                            + (((ks * 4 + quad) ^ swz) * 8)];
                oacc[ht] = __builtin_amdgcn_mfma_f32_16x16x32_bf16(pf, vf, oacc[ht], 0, 0, 0);
            }
        }
        p ^= 1;
    }

    const int nch = (qt64 + 8) >> 3;
    if (nch == 1) {
        // single chunk: write final output directly
#pragma unroll
        for (int r = 0; r < 4; ++r) {
            float inv = 1.0f / l_run[r];
            float* orow = out + (size_t)(b * T_SEQ + qrow0 + quad * 4 + r) * HDIM;
#pragma unroll
            for (int ht = 0; ht < 4; ++ht)
                orow[ht * 16 + l16] = oacc[ht][r] * inv;
        }
        return;
    }

    // write partials
    const int pbase = b * PPB + cum;
    const int pidx  = pbase + c;
    float* obase = Op + (size_t)pidx * 4096;
#pragma unroll
    for (int ht = 0; ht < 4; ++ht)
#pragma unroll
        for (int r = 0; r < 4; ++r)
            obase[(wave * 16 + quad * 4 + r) * 64 + ht * 16 + l16] = oacc[ht][r];
    if (l16 == 0)
#pragma unroll
        for (int r = 0; r < 4; ++r)
            mlp[(size_t)pidx * 64 + wave * 16 + quad * 4 + r] = make_float2(m_run[r], l_run[r]);

    // last-finisher merge
    __threadfence();
    __syncthreads();
    if (tid == 0) lastv = atomicAdd(&cnt[b * 32 + qt64], 1);
    __syncthreads();
    if (lastv != nch - 1) return;
    __threadfence();

    const int row = tid >> 2;                   // 0..63
    const int cg4 = tid & 3;
    float2 ml[4];
#pragma unroll
    for (int cc = 0; cc < 4; ++cc) {
        ml[cc] = mlp[(size_t)(pbase + cc) * 64 + row];
        if (cc >= nch) ml[cc].x = -1e30f;
    }
    float M = -1e30f;
#pragma unroll
    for (int cc = 0; cc < 4; ++cc) M = fmaxf(M, ml[cc].x);
    float wgt[4]; float L = 0.f;
#pragma unroll
    for (int cc = 0; cc < 4; ++cc) { wgt[cc] = __expf(ml[cc].x - M); L += ml[cc].y * wgt[cc]; }
    const float inv = 1.0f / L;
#pragma unroll
    for (int pass = 0; pass < 4; ++pass) {
        const int col = (cg4 + pass * 4) * 4;
        float4 O = make_float4(0.f, 0.f, 0.f, 0.f);
#pragma unroll
        for (int cc = 0; cc < 4; ++cc) {
            float4 o4 = *(const float4*)&Op[(size_t)(pbase + cc) * 4096 + row * 64 + col];
            O.x += o4.x * wgt[cc]; O.y += o4.y * wgt[cc];
            O.z += o4.z * wgt[cc]; O.w += o4.w * wgt[cc];
        }
        float4 res = make_float4(O.x * inv, O.y * inv, O.z * inv, O.w * inv);
        *(float4*)&out[((size_t)(b * T_SEQ) + qt64 * 64 + row) * HDIM + col] = res;
    }
}

// ---------------------------------------------------------------------------
extern "C" void kernel_launch(void* const* d_in, const int* in_sizes, int n_in,
                              void* d_out, int out_size, void* d_ws, size_t ws_size,
                              hipStream_t stream) {
    (void)in_sizes; (void)n_in; (void)out_size; (void)ws_size;
    const float* x     = (const float*)d_in[0];
    const float* Wq    = (const float*)d_in[1];
    const float* Wk    = (const float*)d_in[2];
    const float* Wv    = (const float*)d_in[3];
    const float* rbias = (const float*)d_in[4];
    float* out = (float*)d_out;

    char* wsb     = (char*)d_ws;
    short* qb     = (short*)(wsb);                                  // 2 MB
    short* kb     = (short*)(wsb + (size_t)2 * 1024 * 1024);        // 2 MB
    short* vtb    = (short*)(wsb + (size_t)4 * 1024 * 1024);        // 2 MB
    short* Wbt    = (short*)(wsb + (size_t)6 * 1024 * 1024);        // 384 KB
    int*   cnt    = (int*)(wsb + (size_t)6 * 1024 * 1024 + 512 * 1024);  // 1 KB
    short* biasPk = (short*)(wsb + (size_t)7 * 1024 * 1024);        // 4.33 MB
    float* Op     = (float*)(wsb + (size_t)12 * 1024 * 1024);       // 10 MB
    float2* mlp   = (float2*)(wsb + (size_t)23 * 1024 * 1024);      // 320 KB

    hipMemsetAsync(cnt, 0, NB * 32 * sizeof(int), stream);
    prep_kernel<<<dim3(128, 8), 256, 0, stream>>>(Wq, Wk, Wv, rbias, Wbt, biasPk);
    proj_kernel<<<dim3(512), 512, 0, stream>>>(x, Wbt, qb, kb, vtb);
    attn_kernel<<<dim3(PPB, NB), 256, 0, stream>>>(qb, kb, vtb, biasPk, Op, mlp, cnt, out);
}

// Round 8
// 171.781 us; speedup vs baseline: 1.5883x; 1.5883x over previous
//
#include <hip/hip_runtime.h>

#define T_SEQ 2048
#define NB    8
#define CDIM  1024
#define HDIM  64
#define PPB   80   // partials per batch: sum_{i<32} ceil((i+1)/8)

typedef __attribute__((ext_vector_type(8))) short short8;
typedef __attribute__((ext_vector_type(4))) short short4v;
typedef __attribute__((ext_vector_type(4))) float float4v;

// f32 -> bf16 bits, round-to-nearest-even
__device__ inline short f2bf(float x) {
    unsigned u = __builtin_bit_cast(unsigned int, x);
    u += 0x7FFFu + ((u >> 16) & 1u);
    return (short)(u >> 16);
}
__device__ inline float bf2f(short v) {
    return __builtin_bit_cast(float, ((unsigned)(unsigned short)v) << 16);
}

// async global->LDS DMA, 16 bytes per lane (global_load_lds_dwordx4)
__device__ inline void dma16(const void* g, void* l) {
    __builtin_amdgcn_global_load_lds(
        (const __attribute__((address_space(1))) unsigned int*)g,
        (__attribute__((address_space(3))) unsigned int*)l, 16, 0, 0);
}

// DPP lane-permute within 16-lane rows (VALU pipe, no LDS)
template<int CTRL> __device__ inline float dppf(float v) {
    return __builtin_bit_cast(float,
        __builtin_amdgcn_update_dpp(0, __builtin_bit_cast(int, v), CTRL, 0xF, 0xF, true));
}
__device__ inline float rowmax16(float v) {
    v = fmaxf(v, dppf<0xB1>(v));  v = fmaxf(v, dppf<0x4E>(v));
    v = fmaxf(v, dppf<0x141>(v)); v = fmaxf(v, dppf<0x140>(v));
    return v;
}
__device__ inline float rowsum16(float v) {
    v += dppf<0xB1>(v);  v += dppf<0x4E>(v);
    v += dppf<0x141>(v); v += dppf<0x140>(v);
    return v;
}

// ---------------------------------------------------------------------------
// Kernel 1: fused prep.
//  (a) blocks (qt16<48, jy==0): Wq|Wk|Wv -> Wbt (192,1024) bf16 transposed.
//  (b) all blocks: packed pre-masked bf16 bias, per-lane fragment order.
//      Layout: slot*1024 + lane*8 holds frags nt=0,1; +512 holds nt=2,3
//      (each wave bias load = two coalesced 1KB dwordx4 bursts).
//      Masked entries = -1e38 (exp underflows to exact 0 in attn).
// grid (128, 8), block 256; wave w handles j = jy*4+w.
// ---------------------------------------------------------------------------
__global__ __launch_bounds__(256) void prep_kernel(
    const float* __restrict__ Wq, const float* __restrict__ Wk,
    const float* __restrict__ Wv, const float* __restrict__ rbias,
    short* __restrict__ Wbt, short* __restrict__ biasPk)
{
    const int qt16 = blockIdx.x;
    const int tid  = threadIdx.x;
    const int wave = tid >> 6, lane = tid & 63;
    const int quad = lane >> 4, l16 = lane & 15;

    if (blockIdx.y == 0 && qt16 < 48) {          // (a) weight convert
        __shared__ float tile[64][65];
        const int w  = qt16 >> 4;
        const int k0 = (qt16 & 15) * 64;
        const float* Ws[3] = {Wq, Wk, Wv};
        const float* W = Ws[w];
        const int n  = tid & 63;
        const int kq = tid >> 6;
#pragma unroll
        for (int i = 0; i < 16; ++i)
            tile[kq + i * 4][n] = W[(size_t)(k0 + kq + i * 4) * HDIM + n];
        __syncthreads();
        const int kk = tid & 63;
#pragma unroll
        for (int i = 0; i < 16; ++i) {
            int nn = kq + i * 4;
            Wbt[((size_t)(w * HDIM + nn)) * CDIM + k0 + kk] = f2bf(tile[kk][nn]);
        }
    }

    const int a  = qt16 >> 2;
    const int jw = (int)blockIdx.y * 4 + wave;
    if (jw <= a) {                                // (b) bias pack
        const short SENT = f2bf(-1e38f);
        short8 lo, hi;
#pragma unroll
        for (int nt = 0; nt < 4; ++nt) {
            const int s = jw * 64 + nt * 16 + l16;
#pragma unroll
            for (int r = 0; r < 4; ++r) {
                const int t = qt16 * 16 + quad * 4 + r;
                float rb = rbias[(size_t)t * T_SEQ + s];
                bool ok = (rb > 0.f) || ((t == 0) && (s == 0));
                short v = ok ? f2bf(rb) : SENT;
                if (nt < 2) lo[nt * 4 + r] = v; else hi[(nt - 2) * 4 + r] = v;
            }
        }
        short* dst = biasPk + ((size_t)((2 * a + (qt16 & 3)) * (a + 1) + jw)) * 1024
                   + lane * 8;
        *(short8*)dst = lo;
        *(short8*)(dst + 512) = hi;
    }
}

// ---------------------------------------------------------------------------
// Kernel 2: projection GEMM. grid 512, block 512 = 8 waves (2 blocks/CU).
// Wave (mt, cg) computes m-tile mt x col-tiles {3cg..3cg+2}. B via DMA,
// A cooperative load+cvt. XOR-swizzled LDS chunks. q pre-scaled by 1/32.
// ---------------------------------------------------------------------------
__global__ __launch_bounds__(512) void proj_kernel(
    const float* __restrict__ x, const short* __restrict__ Wbt,
    short* __restrict__ qb, short* __restrict__ kb, short* __restrict__ vtb)
{
    __shared__ short As[2][32 * 64];
    __shared__ short Bs[2][192 * 64];

    const int tid  = threadIdx.x;
    const int wave = tid >> 6, lane = tid & 63;
    const int quad = lane >> 4, l16 = lane & 15;
    const int mt   = wave >> 2;
    const int cg   = wave & 3;
    const int m0   = blockIdx.x * 32;

    const int arow = tid >> 4;
    const int ac   = tid & 15;
    const int asw  = (((ac >> 1) ^ (arow & 7)) * 8) + (ac & 1) * 4;
    const float* xsrc = x + (size_t)(m0 + arow) * CDIM + ac * 4;

    const int brow = tid >> 3;
    const int bsw  = ((tid & 7) ^ (brow & 7)) * 8;

    float4v acc[3];
#pragma unroll
    for (int i = 0; i < 3; ++i) acc[i] = (float4v){0.f, 0.f, 0.f, 0.f};

    {
        float4 a = *(const float4*)xsrc;
#pragma unroll
        for (int i = 0; i < 3; ++i)
            dma16(Wbt + (size_t)(i * 64 + brow) * CDIM + bsw,
                  &Bs[0][i * 4096 + tid * 8]);
        short4v s; s[0]=f2bf(a.x); s[1]=f2bf(a.y); s[2]=f2bf(a.z); s[3]=f2bf(a.w);
        *(short4v*)&As[0][arow * 64 + asw] = s;
    }

    int p = 0;
    for (int kt = 0; kt < 16; ++kt) {
        __syncthreads();
        const bool more = (kt + 1) < 16;
        float4 a;
        if (more) {
            a = *(const float4*)(xsrc + (kt + 1) * 64);
#pragma unroll
            for (int i = 0; i < 3; ++i)
                dma16(Wbt + (size_t)(i * 64 + brow) * CDIM + (kt + 1) * 64 + bsw,
                      &Bs[p ^ 1][i * 4096 + tid * 8]);
        }
#pragma unroll
        for (int ks = 0; ks < 2; ++ks) {
            const int cs = ((ks * 4 + quad) ^ (l16 & 7)) * 8;
            short8 af = *(const short8*)&As[p][(mt * 16 + l16) * 64 + cs];
#pragma unroll
            for (int i = 0; i < 3; ++i) {
                const int ct = cg * 3 + i;
                short8 bf_ = *(const short8*)&Bs[p][(ct * 16 + l16) * 64 + cs];
                acc[i] = __builtin_amdgcn_mfma_f32_16x16x32_bf16(af, bf_, acc[i], 0, 0, 0);
            }
        }
        if (more) {
            short4v s; s[0]=f2bf(a.x); s[1]=f2bf(a.y); s[2]=f2bf(a.z); s[3]=f2bf(a.w);
            *(short4v*)&As[p ^ 1][arow * 64 + asw] = s;
        }
        p ^= 1;
    }

#pragma unroll
    for (int i = 0; i < 3; ++i) {
        const int ctg = cg * 3 + i;
        const int mat = ctg >> 2;
        const int n   = (ctg & 3) * 16 + l16;
#pragma unroll
        for (int r = 0; r < 4; ++r) {
            const int m = m0 + mt * 16 + quad * 4 + r;
            if (mat == 0)      qb[(size_t)m * HDIM + n] = f2bf(acc[i][r] * 0.03125f);
            else if (mat == 1) kb[(size_t)m * HDIM + n] = f2bf(acc[i][r]);
            else {
                int bb = m >> 11, tt = m & (T_SEQ - 1);
                vtb[((size_t)bb * HDIM + n) * T_SEQ + tt] = f2bf(acc[i][r]);
            }
        }
    }
}

// ---------------------------------------------------------------------------
// Kernel 3: flash attention partials (R6 structure — NO fences/atomics).
// Bias via 2 coalesced dwordx4 loads of packed pre-masked bf16.
// Writes partials; separate merge kernel provides device-scope coherence
// at the kernel boundary (no mid-dispatch L2 flushes).
// ---------------------------------------------------------------------------
__global__ __launch_bounds__(256) void attn_part_kernel(
    const short* __restrict__ qb, const short* __restrict__ kb,
    const short* __restrict__ vtb, const short* __restrict__ biasPk,
    float* __restrict__ Op, float2* __restrict__ mlp)
{
    __shared__ short Ks[2][64 * 64];
    __shared__ short Vs[2][64 * 64];
    __shared__ short Ps[4][16][72];

    const int b   = blockIdx.y;
    const int tid = threadIdx.x;
    const int wave = tid >> 6, lane = tid & 63;
    const int quad = lane >> 4, l16 = lane & 15;
    const int swz  = l16 & 7;
    const int srow = tid >> 3;
    const int gchk = ((tid & 7) ^ (srow & 7)) * 8;

    const int bx = (int)(gridDim.x - 1 - blockIdx.x);   // heavy tasks first
    int qt64 = 0, c = bx, cum = 0;
    while (true) { int ch = (qt64 + 8) >> 3; if (c < ch) break; c -= ch; cum += ch; ++qt64; }
    const int j0 = c * 8;
    const int j1 = (j0 + 8 < qt64 + 1) ? j0 + 8 : qt64 + 1;
    const int qrow0 = qt64 * 64 + wave * 16;
    const size_t boff = (size_t)(2 * qt64 + wave) * (qt64 + 1);

    const short* qptr = qb + (size_t)(b * T_SEQ + qrow0 + l16) * HDIM;
    short8 qf0 = *(const short8*)(qptr + quad * 8);
    short8 qf1 = *(const short8*)(qptr + 32 + quad * 8);

    float4v oacc[4];
#pragma unroll
    for (int i = 0; i < 4; ++i) oacc[i] = (float4v){0.f, 0.f, 0.f, 0.f};
    float m_run[4] = {-1e30f, -1e30f, -1e30f, -1e30f};
    float l_run[4] = {0.f, 0.f, 0.f, 0.f};

    {   // prologue: stage tile j0 into buffer 0
        const int s0 = j0 * 64;
#pragma unroll
        for (int i = 0; i < 2; ++i) {
            dma16(kb + (size_t)(b * T_SEQ + s0 + i * 32 + srow) * HDIM + gchk,
                  &Ks[0][i * 2048 + tid * 8]);
            dma16(vtb + (size_t)(b * HDIM + i * 32 + srow) * T_SEQ + s0 + gchk,
                  &Vs[0][i * 2048 + tid * 8]);
        }
    }

    int p = 0;
    for (int j = j0; j < j1; ++j) {
        __syncthreads();

        // 1. packed bias: 2 coalesced 16B loads (oldest VMEM -> their wait
        //    leaves the KV prefetch DMAs in flight)
        const short* bp = biasPk + (boff + j) * 1024 + lane * 8;
        short8 bl0 = *(const short8*)bp;
        short8 bl1 = *(const short8*)(bp + 512);

        // 2. prefetch next KV tile
        if (j + 1 < j1) {
            const int sn = (j + 1) * 64;
#pragma unroll
            for (int i = 0; i < 2; ++i) {
                dma16(kb + (size_t)(b * T_SEQ + sn + i * 32 + srow) * HDIM + gchk,
                      &Ks[p ^ 1][i * 2048 + tid * 8]);
                dma16(vtb + (size_t)(b * HDIM + i * 32 + srow) * T_SEQ + sn + gchk,
                      &Vs[p ^ 1][i * 2048 + tid * 8]);
            }
        }

        // 3. S = Q K^T from LDS (swizzled chunks)
        float4v sa[4];
#pragma unroll
        for (int nt = 0; nt < 4; ++nt) {
            const int rbase = (nt * 16 + l16) * 64;
            short8 kf0 = *(const short8*)&Ks[p][rbase + ((quad ^ swz) * 8)];
            short8 kf1 = *(const short8*)&Ks[p][rbase + (((4 + quad) ^ swz) * 8)];
            float4v acc_ = {0.f, 0.f, 0.f, 0.f};
            acc_ = __builtin_amdgcn_mfma_f32_16x16x32_bf16(qf0, kf0, acc_, 0, 0, 0);
            acc_ = __builtin_amdgcn_mfma_f32_16x16x32_bf16(qf1, kf1, acc_, 0, 0, 0);
            sa[nt] = acc_;
        }

        // 4. bias add (pre-masked) + online softmax; masked = -1e38 -> exp = 0
        float pm[4][4];
        float mt[4] = {-1e30f, -1e30f, -1e30f, -1e30f};
#pragma unroll
        for (int nt = 0; nt < 4; ++nt)
#pragma unroll
            for (int r = 0; r < 4; ++r) {
                short rv = (nt < 2) ? bl0[nt * 4 + r] : bl1[(nt - 2) * 4 + r];
                float sv = sa[nt][r] + bf2f(rv);
                pm[nt][r] = sv;
                mt[r] = fmaxf(mt[r], sv);
            }
        float alpha[4];
#pragma unroll
        for (int r = 0; r < 4; ++r) {
            float mn = fmaxf(m_run[r], rowmax16(mt[r]));
            alpha[r] = __expf(m_run[r] - mn);
            m_run[r] = mn;
        }
        float rs[4] = {0.f, 0.f, 0.f, 0.f};
#pragma unroll
        for (int nt = 0; nt < 4; ++nt)
#pragma unroll
            for (int r = 0; r < 4; ++r) {
                float pv = __expf(pm[nt][r] - m_run[r]);
                pm[nt][r] = pv;
                rs[r] += pv;
            }
#pragma unroll
        for (int r = 0; r < 4; ++r) {
            l_run[r] = l_run[r] * alpha[r] + rowsum16(rs[r]);
            oacc[0][r] *= alpha[r]; oacc[1][r] *= alpha[r];
            oacc[2][r] *= alpha[r]; oacc[3][r] *= alpha[r];
        }

        // 5. P (C-layout) -> per-wave LDS -> A-layout; O += P V
#pragma unroll
        for (int nt = 0; nt < 4; ++nt)
#pragma unroll
            for (int r = 0; r < 4; ++r)
                Ps[wave][quad * 4 + r][nt * 16 + l16] = f2bf(pm[nt][r]);

#pragma unroll
        for (int ks = 0; ks < 2; ++ks) {
            short8 pf = *(const short8*)&Ps[wave][l16][ks * 32 + quad * 8];
#pragma unroll
            for (int ht = 0; ht < 4; ++ht) {
                short8 vf = *(const short8*)&Vs[p][(ht * 16 + l16) * 64
                            + (((ks * 4 + quad) ^ swz) * 8)];
                oacc[ht] = __builtin_amdgcn_mfma_f32_16x16x32_bf16(pf, vf, oacc[ht], 0, 0, 0);
            }
        }
        p ^= 1;
    }

    const int pidx = b * PPB + cum + c;
    float* obase = Op + (size_t)pidx * 4096;
#pragma unroll
    for (int ht = 0; ht < 4; ++ht)
#pragma unroll
        for (int r = 0; r < 4; ++r)
            obase[(wave * 16 + quad * 4 + r) * 64 + ht * 16 + l16] = oacc[ht][r];
    if (l16 == 0)
#pragma unroll
        for (int r = 0; r < 4; ++r)
            mlp[(size_t)pidx * 64 + wave * 16 + quad * 4 + r] = make_float2(m_run[r], l_run[r]);
}

// ---------------------------------------------------------------------------
// Kernel 4: merge partials. One float4 slot/thread, fixed 4-wide chunk loop
// with exp(-inf)=0 masking.
// ---------------------------------------------------------------------------
__global__ __launch_bounds__(256) void attn_merge_kernel(
    const float* __restrict__ Op, const float2* __restrict__ mlp,
    float* __restrict__ out)
{
    const int qt16 = blockIdx.x;
    const int b    = blockIdx.y;
    const int qt64 = qt16 >> 2;
    const int nch  = (qt64 + 8) >> 3;
    const int g8   = qt64 >> 3, rem = qt64 & 7;
    const int cum  = 4 * g8 * (g8 + 1) + rem * (g8 + 1);
    const int pbase = b * PPB + cum;

    const int row = threadIdx.x >> 4;
    const int c4  = (threadIdx.x & 15) * 4;
    const int prow = (qt16 & 3) * 16 + row;

    float2 ml[4];
    float4 o4[4];
#pragma unroll
    for (int cc = 0; cc < 4; ++cc) {
        ml[cc] = mlp[(size_t)(pbase + cc) * 64 + prow];
        o4[cc] = *(const float4*)&Op[(size_t)(pbase + cc) * 4096 + prow * 64 + c4];
        if (cc >= nch) ml[cc].x = -1e30f;
    }
    float M = -1e30f;
#pragma unroll
    for (int cc = 0; cc < 4; ++cc) M = fmaxf(M, ml[cc].x);
    float L = 0.f;
    float4 O = make_float4(0.f, 0.f, 0.f, 0.f);
#pragma unroll
    for (int cc = 0; cc < 4; ++cc) {
        float w = __expf(ml[cc].x - M);
        L += ml[cc].y * w;
        O.x += o4[cc].x * w; O.y += o4[cc].y * w;
        O.z += o4[cc].z * w; O.w += o4[cc].w * w;
    }
    float inv = 1.0f / L;
    float4 res = make_float4(O.x * inv, O.y * inv, O.z * inv, O.w * inv);
    *(float4*)&out[((size_t)(b * T_SEQ) + qt16 * 16 + row) * HDIM + c4] = res;
}

// ---------------------------------------------------------------------------
extern "C" void kernel_launch(void* const* d_in, const int* in_sizes, int n_in,
                              void* d_out, int out_size, void* d_ws, size_t ws_size,
                              hipStream_t stream) {
    (void)in_sizes; (void)n_in; (void)out_size; (void)ws_size;
    const float* x     = (const float*)d_in[0];
    const float* Wq    = (const float*)d_in[1];
    const float* Wk    = (const float*)d_in[2];
    const float* Wv    = (const float*)d_in[3];
    const float* rbias = (const float*)d_in[4];
    float* out = (float*)d_out;

    char* wsb     = (char*)d_ws;
    short* qb     = (short*)(wsb);                                  // 2 MB
    short* kb     = (short*)(wsb + (size_t)2 * 1024 * 1024);        // 2 MB
    short* vtb    = (short*)(wsb + (size_t)4 * 1024 * 1024);        // 2 MB
    short* Wbt    = (short*)(wsb + (size_t)6 * 1024 * 1024);        // 384 KB
    short* biasPk = (short*)(wsb + (size_t)7 * 1024 * 1024);        // 4.45 MB
    float* Op     = (float*)(wsb + (size_t)12 * 1024 * 1024);       // 10 MB
    float2* mlp   = (float2*)(wsb + (size_t)23 * 1024 * 1024);      // 320 KB

    prep_kernel<<<dim3(128, 8), 256, 0, stream>>>(Wq, Wk, Wv, rbias, Wbt, biasPk);
    proj_kernel<<<dim3(512), 512, 0, stream>>>(x, Wbt, qb, kb, vtb);
    attn_part_kernel<<<dim3(PPB, NB), 256, 0, stream>>>(qb, kb, vtb, biasPk, Op, mlp);
    attn_merge_kernel<<<dim3(128, NB), 256, 0, stream>>>(Op, mlp, out);
}